// Round 6
// baseline (189.787 us; speedup 1.0000x reference)
//
#include <hip/hip_runtime.h>

// HausdorffDTLoss: exact separable EDT (fg & bg) per image, then
// mean((pred-target)^2 * (pred_dt^2 + target_dt^2)).
// Envelope identity: g[i] = min_j f[j]+(i-j)^2 = i^2 + min_j (h[j]-2ij),
// h[j]=f[j]+j^2. All intermediates are integers, |val| < 2^17 -> u16 storage,
// fp32 math exact (R1-R14: absmax 0.0).
// R12 windowing: scan only |i-j| <= W, W = ceil(sqrt(max f over outputs)) --
// exact for any input (j=i in-window; outside candidates >= f(i) >= g(i)).
//
// R15. R14: 182us (zy 77, VALUBusy 51%, VGPR still 24 -- the reg-batched
// stage was re-scheduled away; stage ILP theory dead). Issue-bound floor for
// zy is ~25-38us -> stalls are ~2x. This round:
//  - xloss REBUILD (biggest lever): 512thr/64-col tiles makes i0=(tid>>6)*16
//    wave-uniform -> window K drops 32->16 rows (trip 46->30); A/B polarity
//    volumes fused into ONE u32-packed LDS scan (A|B<<16 per voxel): one
//    u32-vectorized stage, ONE barrier (was 3), one window, one scan updating
//    accA+accB. ~4400 -> ~2600 inst/thread. sqrt-then-square kept (reference
//    computes (sqrt g)**2 -- bit-compat).
//  - zy: 2-deep LDS prefetch ring in the envelope (issue slack 280cyc >> 120
//    cyc LDS latency) to attack the lgkm-wait share of the 49% stall.

constexpr int BIGI = 49153;      // 3*128^2+1, matches reference BIG exactly
constexpr int NVOX = 4194304;    // voxels per tensor (2 samples x 128^3)
constexpr int STZ  = 129;        // zy dword row stride: 129%32=1 -> 2-way max (free)
constexpr int STX  = 65;         // xloss dword row stride: 65%32=1 -> same property

__global__ void zero_kernel(float* out, int* flags) {
    out[0] = 0.0f;
    flags[0] = 0; flags[1] = 0; flags[2] = 0; flags[3] = 0;
}

// Windowed pair-packed lower-envelope into acc[16] at outputs i0..i0+15.
// p = column c of a [68*stride] u32 LDS array of packed u16 h-values
// (rows qhi+1, qhi+2 exist as slack). 2-deep read-ahead ring.
__device__ __forceinline__ void envelope_win(const unsigned int* __restrict__ p,
                                             const int stride, const float i0f,
                                             const int qlo, const int qhi,
                                             float acc[16]) {
    unsigned int vc = p[qlo * stride];
    unsigned int vn = p[(qlo + 1) * stride];
    float jm2 = -4.0f * (float)qlo;            // -2*(2q)
    for (int q = qlo; q <= qhi; ++q) {
        unsigned int vf = p[(q + 2) * stride]; // 2-ahead prefetch
        float h0 = (float)(vc & 0xffffu);      // j = 2q
        float h1 = (float)(vc >> 16);          // j = 2q+1
        float jb = jm2 - 2.0f;
        float c0 = fmaf(jm2, i0f, h0);         // candidate at i = i0
        float c1 = fmaf(jb,  i0f, h1);
#pragma unroll
        for (int k = 0; k < 16; ++k) {
            acc[k] = fminf(acc[k], fminf(c0, c1));
            c0 += jm2; c1 += jb;               // exact: integers < 2^17
        }
        jm2 -= 4.0f;
        vc = vn; vn = vf;
    }
}

// Wave-uniform window W from the wave's 16 output rows' f-values (pair-packed
// layout; f = h - i^2), wave-maxed. Guarantees W*W >= fmax.
__device__ __forceinline__ int window_of(const unsigned int* __restrict__ p,
                                         const int stride, const int i0) {
    int fmx = 0;
#pragma unroll
    for (int m = 0; m < 8; ++m) {
        unsigned int v = p[((i0 >> 1) + m) * stride];
        int y0 = i0 + 2 * m, y1 = y0 + 1;
        int f0 = (int)(v & 0xffffu) - y0 * y0;
        int f1 = (int)(v >> 16) - y1 * y1;
        fmx = max(fmx, max(f0, f1));
    }
#pragma unroll
    for (int off = 32; off; off >>= 1) fmx = max(fmx, __shfl_xor(fmx, off));
    int W = (int)sqrtf((float)fmx);            // fmx <= 49153, exact in fp32
    W += (W * W < fmx);
    W += (W * W < fmx);                        // guarantees W*W >= fmx
    return W;
}

// Fused binarize + parallel bitmask z-EDT + windowed y-envelope for one (b,x)
// slab of one image, one polarity. 512 thr, 37.1KB LDS, 4 blocks/CU
// (thread-capped). Grid 1024 = (pol, img, b*x).
__global__ __launch_bounds__(512) void zy_kernel(const float* __restrict__ pred,
                                                 const float* __restrict__ tgt,
                                                 unsigned short* __restrict__ ws,
                                                 int* __restrict__ flags) {
    __shared__ unsigned int hz[68 * STZ];          // packed u16 pairs + slack rows
    __shared__ unsigned long long bm[256];         // site bitmasks: [y][z-half]
    const int t   = blockIdx.x;
    const int pol = t & 1;                         // 0: fg EDT (sites=~fg), 1: bg
    const int img = (t >> 1) & 1;
    const int s   = t >> 2;                        // 0..255: b(2) x x(128)
    const int b   = s >> 7;
    const int x   = s & 127;
    const int sb  = (b * 128 + x) * 16384;         // + y*128 + z
    const int tid = threadIdx.x;
    const float* im = img ? tgt : pred;

    // ---- stage: coalesced read -> per-wave ballot -> site bitmasks ----
    bool anyfg = false;
#pragma unroll
    for (int k = 0; k < 32; ++k) {
        int l = tid + k * 512;
        float v = im[sb + l];
        bool fg = v > 0.5f;
        anyfg |= fg;
        bool site = pol ? fg : !fg;
        unsigned long long bal = __ballot(site);
        if ((tid & 63) == 0) bm[l >> 6] = bal;     // l>>6 uniform per wave
    }
    if (!pol && __ballot(anyfg) != 0ULL && (tid & 63) == 0)
        atomicOr(flags + img * 2 + b, 1);
    __syncthreads();

    // ---- parallel z-EDT: per-voxel nearest-site distance from the masks ----
    unsigned short* hu = (unsigned short*)hz;
    const int z = tid & 127;                       // fixed per thread, uniform/wave
#pragma unroll
    for (int k = 0; k < 32; ++k) {
        int y = (tid >> 7) + k * 4;
        unsigned long long m0 = bm[2 * y], m1 = bm[2 * y + 1];
        int d;
        if (z < 64) {
            unsigned long long lm = m0 << (63 - z);
            unsigned long long rm = m0 >> z;
            int dfwd = lm ? __builtin_clzll(lm) : 999;
            int db0  = rm ? __builtin_ctzll(rm) : 999;
            int db1  = (m1 ? __builtin_ctzll(m1) : 999) + (64 - z);
            d = min(dfwd, min(db0, db1));
        } else {
            int zz = z - 64;
            unsigned long long lm = m1 << (63 - zz);
            unsigned long long rm = m1 >> zz;
            int df1 = lm ? __builtin_clzll(lm) : 999;
            int df0 = (m0 ? __builtin_clzll(m0) : 999) + zz + 1;
            int dbw = rm ? __builtin_ctzll(rm) : 999;
            d = min(min(df1, df0), dbw);
        }
        int f = (d <= 127) ? d * d : BIGI;         // empty line -> BIG (exact)
        hu[((y >> 1) * STZ) * 2 + (y & 1) + 2 * z] = (unsigned short)(f + y * y);
    }
    __syncthreads();

    // ---- y-envelope: c = z column, 4 groups x 2 rounds; store g + x^2 ----
    unsigned short* outv = ws + (size_t)(img * 2 + pol) * NVOX + sb;
    const int c = tid & 127;
    const int xsq = x * x;
#pragma clang loop unroll(disable)
    for (int r = 0; r < 2; ++r) {                  // one acc[16] live at a time
        const int i0 = (tid >> 7) * 16 + r * 64;   // wave-uniform (tid>>7)
        const float i0f = (float)i0;
        const int W = window_of(hz + c, STZ, i0);
        const int qlo = __builtin_amdgcn_readfirstlane(max(0, (i0 - W) >> 1));
        const int qhi = __builtin_amdgcn_readfirstlane(min(63, (i0 + 15 + W) >> 1));
        float acc[16];
#pragma unroll
        for (int k = 0; k < 16; ++k) acc[k] = 3.0e38f;
        envelope_win(hz + c, STZ, i0f, qlo, qhi, acc);
#pragma unroll
        for (int k = 0; k < 16; ++k) {             // g + x^2 <= 65282: u16
            float iif = i0f + (float)k;
            outv[(i0 + k) * 128 + c] =
                (unsigned short)((unsigned int)fmaf(iif, iif, acc[k]) + xsq);
        }
    }
}

// Fused dual-polarity x-envelope + loss partial. 64-col tiles, 512 thr,
// 33.8KB LDS, 4 blocks/CU. Grid 1024 = (img, b, 256 tiles).
// LDS word [j][c] = hA | hB<<16 (per-row layout, NOT pair-packed): both
// polarity volumes scanned in ONE pass; i0=(tid>>6)*16 is exactly
// wave-uniform -> K=16 window span (vs 32 at 256thr). One barrier.
__global__ __launch_bounds__(512) void xloss_kernel(const float* __restrict__ pred,
                                                    const float* __restrict__ tgt,
                                                    const unsigned short* __restrict__ ws,
                                                    const int* __restrict__ flags,
                                                    float* __restrict__ out) {
    __shared__ unsigned int hx[130 * STX];     // rows 0..127 data + 2 slack
    __shared__ float red[8];
    const int t    = blockIdx.x;
    const int img  = t & 1;                    // adjacent blocks share pred/tgt
    const int b    = (t >> 1) & 1;
    const int q0   = (t >> 2) * 64;            // (y,z) tile base, 0..16320
    const int base = b * 2097152 + q0;         // + x*16384 + c
    const int tid  = threadIdx.x;
    const int c    = tid & 63;
    const int i0   = (tid >> 6) * 16;          // wave-uniform (64 lanes = 64 cols)
    const float i0f = (float)i0;
    unsigned short* hu = (unsigned short*)hx;
    const unsigned short* A16 = ws + (size_t)(img * 2) * NVOX;
    const unsigned int* A32 = (const unsigned int*)(A16 + base);         // base even
    const unsigned int* B32 = (const unsigned int*)(A16 + NVOX + base);

    // ---- stage BOTH volumes, u32-vectorized: word[j][c] = A | B<<16 ----
#pragma unroll
    for (int k = 0; k < 8; ++k) {
        int l = tid + k * 512;                 // 0..4095
        int j = l >> 5, cp = l & 31;           // row j, u32 col-pair (c=2cp,2cp+1)
        unsigned int va = A32[j * 8192 + cp];
        unsigned int vb = B32[j * 8192 + cp];
        int w0 = (j * STX + 2 * cp) * 2;       // u16 index of word (j, 2cp)
        hu[w0 + 0] = (unsigned short)(va & 0xffffu);   // A half, col 2cp
        hu[w0 + 2] = (unsigned short)(va >> 16);       // A half, col 2cp+1
        hu[w0 + 1] = (unsigned short)(vb & 0xffffu);   // B half, col 2cp
        hu[w0 + 3] = (unsigned short)(vb >> 16);       // B half, col 2cp+1
    }
    __syncthreads();

    // ---- single window over both polarities (superset window = exact) ----
    const unsigned int* p = hx + c;
    int fmx = 0;
#pragma unroll
    for (int m = 0; m < 16; ++m) {
        int j = i0 + m;
        unsigned int w = p[j * STX];
        int h2 = max((int)(w & 0xffffu), (int)(w >> 16));
        fmx = max(fmx, h2 - j * j);            // f = h - j^2 >= 0
    }
#pragma unroll
    for (int off = 32; off; off >>= 1) fmx = max(fmx, __shfl_xor(fmx, off));
    int W = (int)sqrtf((float)fmx);
    W += (W * W < fmx);
    W += (W * W < fmx);                        // W*W >= fmx
    const int jlo = __builtin_amdgcn_readfirstlane(max(0, i0 - W));
    const int jhi = __builtin_amdgcn_readfirstlane(min(127, i0 + 15 + W));

    // ---- fused scan: accA (pol0) + accB (pol1) in one pass, 2-deep ring ----
    float accA[16], accB[16];
#pragma unroll
    for (int k = 0; k < 16; ++k) { accA[k] = 3.0e38f; accB[k] = 3.0e38f; }
    unsigned int vc = p[jlo * STX];
    unsigned int vn = p[(jlo + 1) * STX];
    float jm = -2.0f * (float)jlo;
    for (int j = jlo; j <= jhi; ++j) {
        unsigned int vf = p[(j + 2) * STX];    // slack rows 128..129 exist
        float hA = (float)(vc & 0xffffu);
        float hB = (float)(vc >> 16);
        float cA = fmaf(jm, i0f, hA);          // candidate at i = i0
        float cB = fmaf(jm, i0f, hB);
#pragma unroll
        for (int k = 0; k < 16; ++k) {
            accA[k] = fminf(accA[k], cA);
            accB[k] = fminf(accB[k], cB);
            cA += jm; cB += jm;                // exact: integers < 2^17
        }
        jm -= 2.0f;
        vc = vn; vn = vf;
    }

    // ---- loss partial: (p-t)^2 * (sqrt(gA)+sqrt(gB))^2 * guard ----
    // (sqrt-then-square kept: reference computes (sqrt g)**2, bit-compat)
    float s = 0.0f;
#pragma unroll
    for (int k = 0; k < 16; ++k) {
        float iif = i0f + (float)k;
        float gA = fmaf(iif, iif, accA[k]);
        float gB = fmaf(iif, iif, accB[k]);
        int v = base + (i0 + k) * 16384 + c;   // 256B contiguous per wave
        float d = pred[v] - tgt[v];
        float fld = sqrtf(gA) + sqrtf(gB);
        s += d * d * fld * fld;
    }
    if (!flags[img * 2 + b]) s = 0.0f;
#pragma unroll
    for (int off = 32; off > 0; off >>= 1) s += __shfl_down(s, off);
    if ((tid & 63) == 0) red[tid >> 6] = s;
    __syncthreads();
    if (tid == 0) {
        float tot = 0.0f;
#pragma unroll
        for (int w = 0; w < 8; ++w) tot += red[w];
        atomicAdd(out, tot * (1.0f / 4194304.0f));
    }
}

extern "C" void kernel_launch(void* const* d_in, const int* in_sizes, int n_in,
                              void* d_out, int out_size, void* d_ws, size_t ws_size,
                              hipStream_t stream) {
    const float* pred = (const float*)d_in[0];
    const float* tgt  = (const float*)d_in[1];
    float* out = (float*)d_out;
    unsigned short* ws16 = (unsigned short*)d_ws;  // 4 u16 volumes = 33.6 MB
    int* flags = (int*)(ws16 + 4 * (size_t)NVOX);  // [img0_b0, img0_b1, img1_b0, img1_b1]

    zero_kernel<<<1, 1, 0, stream>>>(out, flags);
    zy_kernel<<<dim3(1024), 512, 0, stream>>>(pred, tgt, ws16, flags);
    xloss_kernel<<<dim3(1024), 512, 0, stream>>>(pred, tgt, ws16, flags, out);
}